// Round 5
// baseline (282.238 us; speedup 1.0000x reference)
//
#include <hip/hip_runtime.h>
#include <math.h>

// RotamerBuilder: fused single-dispatch kernel.
//   blocks [0, KB)     : Kabsch alignment + NeRF extension, 1 thread/residue
//   blocks [KB, KB+CB) : circular-RBF chi embedding, 1 thread = 1 float4
//
// Kabsch via rank-2 closed form (no iterative Jacobi): null vector from best
// row-cross of C, one exact 2x2 Jacobi rotation on the deflated Gram matrix.
// R5: all 45-float coord reads / aligned writes via 4-float vector ops
// (align-4: residue stride 180 B is only dword-aligned) — 11 dwordx4 + 1
// dword per direction instead of 45 scalar dwords.
//
// Layout (out, float32, concatenated):
//   aligned     [N*45]  at offset 0
//   next_coords [N*3]   at offset N*45
//   chi_embed   [N*288] at offset N*48

typedef float f32x4 __attribute__((ext_vector_type(4)));
typedef f32x4 uf32x4 __attribute__((aligned(4)));   // dword-aligned vec4

__device__ __forceinline__ void kabsch_residue(
    const float* __restrict__ fixed, const float* __restrict__ mobile,
    const float* __restrict__ coords, const float* __restrict__ prev,
    const float* __restrict__ blen, const float* __restrict__ bang,
    const float* __restrict__ dihe,
    float* __restrict__ out_aligned, float* __restrict__ out_next, int n) {
  // ---- vector loads of the 9-float triads ----
  const uf32x4* fv = (const uf32x4*)(fixed + (size_t)n * 9);
  const uf32x4* mv = (const uf32x4*)(mobile + (size_t)n * 9);
  f32x4 f0 = fv[0], f1 = fv[1];
  float f8 = fixed[(size_t)n * 9 + 8];
  f32x4 m0 = mv[0], m1 = mv[1];
  float m8 = mobile[(size_t)n * 9 + 8];
  double f[3][3] = {{f0.x, f0.y, f0.z}, {f0.w, f1.x, f1.y}, {f1.z, f1.w, f8}};
  double m[3][3] = {{m0.x, m0.y, m0.z}, {m0.w, m1.x, m1.y}, {m1.z, m1.w, m8}};

  double fc[3], mcm[3];
#pragma unroll
  for (int i = 0; i < 3; ++i) {
    fc[i] = (f[0][i] + f[1][i] + f[2][i]) * (1.0 / 3.0);
    mcm[i] = (m[0][i] + m[1][i] + m[2][i]) * (1.0 / 3.0);
  }
  // Cross-covariance C[i][j] = sum_p (m[p][i]-mcom[i]) * (f[p][j]-fcom[j])
  double C[3][3];
#pragma unroll
  for (int i = 0; i < 3; ++i)
#pragma unroll
    for (int j = 0; j < 3; ++j) {
      double s = 0.0;
#pragma unroll
      for (int p = 0; p < 3; ++p) s += (m[p][i] - mcm[i]) * (f[p][j] - fc[j]);
      C[i][j] = s;
    }

  // --- null vector v3 = best row-cross of C (C has rank <= 2) ---
  double x01 = C[0][1]*C[1][2] - C[0][2]*C[1][1];
  double y01 = C[0][2]*C[1][0] - C[0][0]*C[1][2];
  double z01 = C[0][0]*C[1][1] - C[0][1]*C[1][0];
  double x02 = C[0][1]*C[2][2] - C[0][2]*C[2][1];
  double y02 = C[0][2]*C[2][0] - C[0][0]*C[2][2];
  double z02 = C[0][0]*C[2][1] - C[0][1]*C[2][0];
  double x12 = C[1][1]*C[2][2] - C[1][2]*C[2][1];
  double y12 = C[1][2]*C[2][0] - C[1][0]*C[2][2];
  double z12 = C[1][0]*C[2][1] - C[1][1]*C[2][0];
  double n01 = x01*x01 + y01*y01 + z01*z01;
  double n02 = x02*x02 + y02*y02 + z02*z02;
  double n12 = x12*x12 + y12*y12 + z12*z12;
  double vx = x01, vy = y01, vz = z01, nn = n01;
  if (n02 > nn) { vx = x02; vy = y02; vz = z02; nn = n02; }
  if (n12 > nn) { vx = x12; vy = y12; vz = z12; nn = n12; }
  double invn = 1.0 / sqrt(fmax(nn, 1e-300));
  vx *= invn; vy *= invn; vz *= invn;

  // --- orthonormal basis {w1, w2} of the plane perpendicular to v3 ---
  double av0 = fabs(vx), av1 = fabs(vy), av2 = fabs(vz);
  double w10, w11, w12;
  if (av0 <= av1 && av0 <= av2) {
    w10 = 1.0 - vx*vx; w11 = -vx*vy; w12 = -vx*vz;
  } else if (av1 <= av2) {
    w10 = -vy*vx; w11 = 1.0 - vy*vy; w12 = -vy*vz;
  } else {
    w10 = -vz*vx; w11 = -vz*vy; w12 = 1.0 - vz*vz;
  }
  double iw = 1.0 / sqrt(fmax(w10*w10 + w11*w11 + w12*w12, 1e-300));
  w10 *= iw; w11 *= iw; w12 *= iw;
  double w20 = vy*w12 - vz*w11;
  double w21 = vz*w10 - vx*w12;
  double w22 = vx*w11 - vy*w10;

  // --- b_i = C w_i ; Gram 2x2 ; one exact Jacobi rotation ---
  double b10 = C[0][0]*w10 + C[0][1]*w11 + C[0][2]*w12;
  double b11 = C[1][0]*w10 + C[1][1]*w11 + C[1][2]*w12;
  double b12 = C[2][0]*w10 + C[2][1]*w11 + C[2][2]*w12;
  double b20 = C[0][0]*w20 + C[0][1]*w21 + C[0][2]*w22;
  double b21 = C[1][0]*w20 + C[1][1]*w21 + C[1][2]*w22;
  double b22 = C[2][0]*w20 + C[2][1]*w21 + C[2][2]*w22;
  double g00 = b10*b10 + b11*b11 + b12*b12;
  double g01 = b10*b20 + b11*b21 + b12*b22;
  double g11 = b20*b20 + b21*b21 + b22*b22;
  double c, s;
  if (fabs(g01) > 1e-300) {
    double tau = (g11 - g00) / (2.0 * g01);
    double tt = 1.0 / (fabs(tau) + sqrt(1.0 + tau * tau));
    if (tau < 0.0) tt = -tt;
    c = 1.0 / sqrt(1.0 + tt * tt);
    s = tt * c;
  } else {
    c = 1.0; s = 0.0;
  }
  double va0 = c*w10 - s*w20, va1 = c*w11 - s*w21, va2 = c*w12 - s*w22;
  double vb0 = s*w10 + c*w20, vb1 = s*w11 + c*w21, vb2 = s*w12 + c*w22;
  double Ca0 = c*b10 - s*b20, Ca1 = c*b11 - s*b21, Ca2 = c*b12 - s*b22;
  double Cb0 = s*b10 + c*b20, Cb1 = s*b11 + c*b21, Cb2 = s*b12 + c*b22;

  double ia = 1.0 / sqrt(fmax(Ca0*Ca0 + Ca1*Ca1 + Ca2*Ca2, 1e-300));
  double ua0 = Ca0 * ia, ua1 = Ca1 * ia, ua2 = Ca2 * ia;
  double pr = ua0*Cb0 + ua1*Cb1 + ua2*Cb2;
  double ub0 = Cb0 - pr*ua0, ub1 = Cb1 - pr*ua1, ub2 = Cb2 - pr*ua2;
  double ib = 1.0 / sqrt(fmax(ub0*ub0 + ub1*ub1 + ub2*ub2, 1e-300));
  ub0 *= ib; ub1 *= ib; ub2 *= ib;
  double uc0 = ua1*ub2 - ua2*ub1;
  double uc1 = ua2*ub0 - ua0*ub2;
  double uc2 = ua0*ub1 - ua1*ub0;
  double vc0 = va1*vb2 - va2*vb1;
  double vc1 = va2*vb0 - va0*vb2;
  double vc2 = va0*vb1 - va1*vb0;
  // R = ua va^T + ub vb^T + uc vc^T  (== Kabsch U diag(1,1,det) W^T)
  float r00 = (float)(ua0*va0 + ub0*vb0 + uc0*vc0);
  float r01 = (float)(ua0*va1 + ub0*vb1 + uc0*vc1);
  float r02 = (float)(ua0*va2 + ub0*vb2 + uc0*vc2);
  float r10 = (float)(ua1*va0 + ub1*vb0 + uc1*vc0);
  float r11 = (float)(ua1*va1 + ub1*vb1 + uc1*vc1);
  float r12 = (float)(ua1*va2 + ub1*vb2 + uc1*vc2);
  float r20 = (float)(ua2*va0 + ub2*vb0 + uc2*vc0);
  float r21 = (float)(ua2*va1 + ub2*vb1 + uc2*vc1);
  float r22 = (float)(ua2*va2 + ub2*vb2 + uc2*vc2);
  float mc0 = (float)mcm[0], mc1 = (float)mcm[1], mc2 = (float)mcm[2];
  float fc0 = (float)fc[0], fc1 = (float)fc[1], fc2 = (float)fc[2];

  // ---- aligned = (coords - mob_com) @ R + fixed_com, vectorized I/O ----
  const uf32x4* cv = (const uf32x4*)(coords + (size_t)n * 45);
  float c45[45];
#pragma unroll
  for (int i = 0; i < 11; ++i) {
    f32x4 t = cv[i];
    c45[4 * i + 0] = t.x; c45[4 * i + 1] = t.y;
    c45[4 * i + 2] = t.z; c45[4 * i + 3] = t.w;
  }
  c45[44] = coords[(size_t)n * 45 + 44];

  float o45[45];
#pragma unroll
  for (int a = 0; a < 15; ++a) {
    float x = c45[a * 3 + 0] - mc0;
    float y = c45[a * 3 + 1] - mc1;
    float z = c45[a * 3 + 2] - mc2;
    o45[a * 3 + 0] = x * r00 + y * r10 + z * r20 + fc0;
    o45[a * 3 + 1] = x * r01 + y * r11 + z * r21 + fc1;
    o45[a * 3 + 2] = x * r02 + y * r12 + z * r22 + fc2;
  }
  uf32x4* ov = (uf32x4*)(out_aligned + (size_t)n * 45);
#pragma unroll
  for (int i = 0; i < 11; ++i) {
    f32x4 t;
    t.x = o45[4 * i + 0]; t.y = o45[4 * i + 1];
    t.z = o45[4 * i + 2]; t.w = o45[4 * i + 3];
    __builtin_nontemporal_store(t, &ov[i]);
  }
  out_aligned[(size_t)n * 45 + 44] = o45[44];

  // ---- next_coords (NeRF extension), f32 ----
  const uf32x4* pv = (const uf32x4*)(prev + (size_t)n * 9);
  f32x4 pA = pv[0], pB = pv[1];
  float p8 = prev[(size_t)n * 9 + 8];
  float p00 = pA.x, p01 = pA.y, p02 = pA.z;
  float p10 = pA.w, p11 = pB.x, p12 = pB.y;
  float p20 = pB.z, p21 = pB.w, p22 = p8;
  float bc0 = p10 - p20, bc1 = p11 - p21, bc2 = p12 - p22;
  float nb = sqrtf(bc0*bc0 + bc1*bc1 + bc2*bc2);
  float inb = 1.0f / (nb + 1e-6f);
  bc0 *= inb; bc1 *= inb; bc2 *= inb;
  float e0 = p10 - p00, e1 = p11 - p01, e2 = p12 - p02;
  float ba0 = e1 * bc2 - e2 * bc1;
  float ba1 = e2 * bc0 - e0 * bc2;
  float ba2 = e0 * bc1 - e1 * bc0;
  float nba = sqrtf(ba0*ba0 + ba1*ba1 + ba2*ba2);
  float inba = 1.0f / (nba + 1e-6f);
  ba0 *= inba; ba1 *= inba; ba2 *= inba;
  float m10 = ba1 * bc2 - ba2 * bc1;
  float m11 = ba2 * bc0 - ba0 * bc2;
  float m12 = ba0 * bc1 - ba1 * bc0;
  float L = blen[n], Aa = bang[n], D = dihe[n];
  float sA = sinf(Aa), cA = cosf(Aa), sD = sinf(D), cD = cosf(D);
  float d1 = L * cA;
  float d2 = L * sA * cD;
  float d3 = -L * sA * sD;
  out_next[(size_t)n * 3 + 0] = p20 + bc0 * d1 + m10 * d2 + ba0 * d3;
  out_next[(size_t)n * 3 + 1] = p21 + bc1 * d1 + m11 * d2 + ba1 * d3;
  out_next[(size_t)n * 3 + 2] = p22 + bc2 * d1 + m12 * d2 + ba2 * d3;
}

__global__ __launch_bounds__(256) void rotamer_fused_kernel(
    const float* __restrict__ fixed, const float* __restrict__ mobile,
    const float* __restrict__ coords, const float* __restrict__ prev,
    const float* __restrict__ blen, const float* __restrict__ bang,
    const float* __restrict__ dihe, const float* __restrict__ degrees,
    float* __restrict__ out_aligned, float* __restrict__ out_next,
    f32x4* __restrict__ out_chi, int N, int KB, int total4) {
  int b = blockIdx.x;
  if (b < KB) {
    int n = b * 256 + threadIdx.x;
    if (n < N)
      kabsch_residue(fixed, mobile, coords, prev, blen, bang, dihe,
                     out_aligned, out_next, n);
    return;
  }
  int g = (b - KB) * 256 + threadIdx.x;
  if (g >= total4) return;
  unsigned ug = (unsigned)g;
  unsigned n = ug / 72u;         // magic-mul
  unsigned rem = ug - n * 72u;
  unsigned k = rem / 18u;        // which angle
  unsigned q = rem - k * 18u;    // which float4 within the 72 bins
  float deg = degrees[n * 4u + k];
  float base = (float)(q * 20u) - 180.0f;
  f32x4 v;
#pragma unroll
  for (int j = 0; j < 4; ++j) {
    float center = base + 5.0f * (float)j;
    float t = deg - center + 180.0f;   // in (-175, 540)
    t = (t < 0.0f) ? t + 360.0f : t;
    t = (t >= 360.0f) ? t - 360.0f : t;
    float dw = t - 180.0f;
    v[j] = __expf(dw * dw * (-1.0f / 12.5f));  // v_exp_f32 path
  }
  __builtin_nontemporal_store(v, &out_chi[g]);  // streaming full-line store
}

extern "C" void kernel_launch(void* const* d_in, const int* in_sizes, int n_in,
                              void* d_out, int out_size, void* d_ws,
                              size_t ws_size, hipStream_t stream) {
  (void)n_in; (void)d_ws; (void)ws_size; (void)out_size;
  const float* fixed = (const float*)d_in[0];
  const float* mobile = (const float*)d_in[1];
  const float* coords = (const float*)d_in[2];
  const float* prev = (const float*)d_in[3];
  const float* blen = (const float*)d_in[4];
  const float* bang = (const float*)d_in[5];
  const float* dihe = (const float*)d_in[6];
  const float* degrees = (const float*)d_in[7];

  int N = in_sizes[0] / 9;
  float* out = (float*)d_out;
  float* out_aligned = out;                     // N*45
  float* out_next = out + (size_t)N * 45;       // N*3
  float* out_chi = out + (size_t)N * 48;        // N*288 (16B aligned)

  int KB = (N + 255) / 256;                     // kabsch blocks (first)
  int total4 = N * 72;
  int CB = (total4 + 255) / 256;                // chi blocks
  rotamer_fused_kernel<<<KB + CB, 256, 0, stream>>>(
      fixed, mobile, coords, prev, blen, bang, dihe, degrees,
      out_aligned, out_next, (f32x4*)out_chi, N, KB, total4);
}

// Round 6
// 135.992 us; speedup vs baseline: 2.0754x; 2.0754x over previous
//
#include <hip/hip_runtime.h>
#include <math.h>

// RotamerBuilder: fused single-dispatch kernel.
//   blocks [0, KB)     : Kabsch alignment + NeRF extension, 1 thread/residue,
//                        coords/aligned staged through LDS so ALL global I/O
//                        of the 72MB+72MB streams is aligned float4 full-line.
//   blocks [KB, KB+CB) : circular-RBF chi embedding, 1 thread = 1 float4
//
// R5 lesson (counters): align-4 nontemporal dwordx4 stores at 180B stride
// caused 784MB vs 541MB HBM writes (partial-line streaming bypasses L2
// write-merge). Fix: cooperative 16B-aligned staging, nontemporal only on
// full-line-aligned streams.
//
// Layout (out, float32, concatenated):
//   aligned     [N*45]  at offset 0
//   next_coords [N*3]   at offset N*45
//   chi_embed   [N*288] at offset N*48

typedef float f32x4 __attribute__((ext_vector_type(4)));

// Compute rotation R (row-major r[i][j] applied as x@R) + coms for residue n.
// Rank-2 closed-form Kabsch in f64: null vector from best row-cross of C,
// one exact 2x2 Jacobi rotation on the deflated Gram matrix.
__device__ __forceinline__ void compute_R(
    const float* __restrict__ fixed, const float* __restrict__ mobile, int n,
    float& r00, float& r01, float& r02, float& r10, float& r11, float& r12,
    float& r20, float& r21, float& r22,
    float& mc0, float& mc1, float& mc2,
    float& fc0, float& fc1, float& fc2) {
  const float* fp = fixed + (size_t)n * 9;
  const float* mp = mobile + (size_t)n * 9;
  double f[3][3], m[3][3];
#pragma unroll
  for (int p = 0; p < 3; ++p)
#pragma unroll
    for (int i = 0; i < 3; ++i) {
      f[p][i] = (double)fp[p * 3 + i];
      m[p][i] = (double)mp[p * 3 + i];
    }
  double fc[3], mcm[3];
#pragma unroll
  for (int i = 0; i < 3; ++i) {
    fc[i] = (f[0][i] + f[1][i] + f[2][i]) * (1.0 / 3.0);
    mcm[i] = (m[0][i] + m[1][i] + m[2][i]) * (1.0 / 3.0);
  }
  double C[3][3];
#pragma unroll
  for (int i = 0; i < 3; ++i)
#pragma unroll
    for (int j = 0; j < 3; ++j) {
      double s = 0.0;
#pragma unroll
      for (int p = 0; p < 3; ++p) s += (m[p][i] - mcm[i]) * (f[p][j] - fc[j]);
      C[i][j] = s;
    }
  // null vector v3 = best row-cross of C (C has rank <= 2)
  double x01 = C[0][1]*C[1][2] - C[0][2]*C[1][1];
  double y01 = C[0][2]*C[1][0] - C[0][0]*C[1][2];
  double z01 = C[0][0]*C[1][1] - C[0][1]*C[1][0];
  double x02 = C[0][1]*C[2][2] - C[0][2]*C[2][1];
  double y02 = C[0][2]*C[2][0] - C[0][0]*C[2][2];
  double z02 = C[0][0]*C[2][1] - C[0][1]*C[2][0];
  double x12 = C[1][1]*C[2][2] - C[1][2]*C[2][1];
  double y12 = C[1][2]*C[2][0] - C[1][0]*C[2][2];
  double z12 = C[1][0]*C[2][1] - C[1][1]*C[2][0];
  double n01 = x01*x01 + y01*y01 + z01*z01;
  double n02 = x02*x02 + y02*y02 + z02*z02;
  double n12 = x12*x12 + y12*y12 + z12*z12;
  double vx = x01, vy = y01, vz = z01, nn = n01;
  if (n02 > nn) { vx = x02; vy = y02; vz = z02; nn = n02; }
  if (n12 > nn) { vx = x12; vy = y12; vz = z12; nn = n12; }
  double invn = 1.0 / sqrt(fmax(nn, 1e-300));
  vx *= invn; vy *= invn; vz *= invn;
  // orthonormal basis {w1,w2} perpendicular to v3
  double av0 = fabs(vx), av1 = fabs(vy), av2 = fabs(vz);
  double w10, w11, w12;
  if (av0 <= av1 && av0 <= av2) {
    w10 = 1.0 - vx*vx; w11 = -vx*vy; w12 = -vx*vz;
  } else if (av1 <= av2) {
    w10 = -vy*vx; w11 = 1.0 - vy*vy; w12 = -vy*vz;
  } else {
    w10 = -vz*vx; w11 = -vz*vy; w12 = 1.0 - vz*vz;
  }
  double iw = 1.0 / sqrt(fmax(w10*w10 + w11*w11 + w12*w12, 1e-300));
  w10 *= iw; w11 *= iw; w12 *= iw;
  double w20 = vy*w12 - vz*w11;
  double w21 = vz*w10 - vx*w12;
  double w22 = vx*w11 - vy*w10;
  // b_i = C w_i ; Gram 2x2 ; one exact Jacobi rotation
  double b10 = C[0][0]*w10 + C[0][1]*w11 + C[0][2]*w12;
  double b11 = C[1][0]*w10 + C[1][1]*w11 + C[1][2]*w12;
  double b12 = C[2][0]*w10 + C[2][1]*w11 + C[2][2]*w12;
  double b20 = C[0][0]*w20 + C[0][1]*w21 + C[0][2]*w22;
  double b21 = C[1][0]*w20 + C[1][1]*w21 + C[1][2]*w22;
  double b22 = C[2][0]*w20 + C[2][1]*w21 + C[2][2]*w22;
  double g00 = b10*b10 + b11*b11 + b12*b12;
  double g01 = b10*b20 + b11*b21 + b12*b22;
  double g11 = b20*b20 + b21*b21 + b22*b22;
  double c, s;
  if (fabs(g01) > 1e-300) {
    double tau = (g11 - g00) / (2.0 * g01);
    double tt = 1.0 / (fabs(tau) + sqrt(1.0 + tau * tau));
    if (tau < 0.0) tt = -tt;
    c = 1.0 / sqrt(1.0 + tt * tt);
    s = tt * c;
  } else {
    c = 1.0; s = 0.0;
  }
  double va0 = c*w10 - s*w20, va1 = c*w11 - s*w21, va2 = c*w12 - s*w22;
  double vb0 = s*w10 + c*w20, vb1 = s*w11 + c*w21, vb2 = s*w12 + c*w22;
  double Ca0 = c*b10 - s*b20, Ca1 = c*b11 - s*b21, Ca2 = c*b12 - s*b22;
  double Cb0 = s*b10 + c*b20, Cb1 = s*b11 + c*b21, Cb2 = s*b12 + c*b22;
  double ia = 1.0 / sqrt(fmax(Ca0*Ca0 + Ca1*Ca1 + Ca2*Ca2, 1e-300));
  double ua0 = Ca0 * ia, ua1 = Ca1 * ia, ua2 = Ca2 * ia;
  double pr = ua0*Cb0 + ua1*Cb1 + ua2*Cb2;
  double ub0 = Cb0 - pr*ua0, ub1 = Cb1 - pr*ua1, ub2 = Cb2 - pr*ua2;
  double ib = 1.0 / sqrt(fmax(ub0*ub0 + ub1*ub1 + ub2*ub2, 1e-300));
  ub0 *= ib; ub1 *= ib; ub2 *= ib;
  double uc0 = ua1*ub2 - ua2*ub1;
  double uc1 = ua2*ub0 - ua0*ub2;
  double uc2 = ua0*ub1 - ua1*ub0;
  double vc0 = va1*vb2 - va2*vb1;
  double vc1 = va2*vb0 - va0*vb2;
  double vc2 = va0*vb1 - va1*vb0;
  r00 = (float)(ua0*va0 + ub0*vb0 + uc0*vc0);
  r01 = (float)(ua0*va1 + ub0*vb1 + uc0*vc1);
  r02 = (float)(ua0*va2 + ub0*vb2 + uc0*vc2);
  r10 = (float)(ua1*va0 + ub1*vb0 + uc1*vc0);
  r11 = (float)(ua1*va1 + ub1*vb1 + uc1*vc1);
  r12 = (float)(ua1*va2 + ub1*vb2 + uc1*vc2);
  r20 = (float)(ua2*va0 + ub2*vb0 + uc2*vc0);
  r21 = (float)(ua2*va1 + ub2*vb1 + uc2*vc1);
  r22 = (float)(ua2*va2 + ub2*vb2 + uc2*vc2);
  mc0 = (float)mcm[0]; mc1 = (float)mcm[1]; mc2 = (float)mcm[2];
  fc0 = (float)fc[0]; fc1 = (float)fc[1]; fc2 = (float)fc[2];
}

__device__ __forceinline__ void nerf_next(
    const float* __restrict__ prev, const float* __restrict__ blen,
    const float* __restrict__ bang, const float* __restrict__ dihe,
    float* __restrict__ out_next, int n) {
  const float* pp = prev + (size_t)n * 9;
  float p00 = pp[0], p01 = pp[1], p02 = pp[2];
  float p10 = pp[3], p11 = pp[4], p12 = pp[5];
  float p20 = pp[6], p21 = pp[7], p22 = pp[8];
  float bc0 = p10 - p20, bc1 = p11 - p21, bc2 = p12 - p22;
  float nb = sqrtf(bc0*bc0 + bc1*bc1 + bc2*bc2);
  float inb = 1.0f / (nb + 1e-6f);
  bc0 *= inb; bc1 *= inb; bc2 *= inb;
  float e0 = p10 - p00, e1 = p11 - p01, e2 = p12 - p02;
  float ba0 = e1 * bc2 - e2 * bc1;
  float ba1 = e2 * bc0 - e0 * bc2;
  float ba2 = e0 * bc1 - e1 * bc0;
  float nba = sqrtf(ba0*ba0 + ba1*ba1 + ba2*ba2);
  float inba = 1.0f / (nba + 1e-6f);
  ba0 *= inba; ba1 *= inba; ba2 *= inba;
  float m10 = ba1 * bc2 - ba2 * bc1;
  float m11 = ba2 * bc0 - ba0 * bc2;
  float m12 = ba0 * bc1 - ba1 * bc0;
  float L = blen[n], Aa = bang[n], D = dihe[n];
  float sA = sinf(Aa), cA = cosf(Aa), sD = sinf(D), cD = cosf(D);
  float d1 = L * cA;
  float d2 = L * sA * cD;
  float d3 = -L * sA * sD;
  out_next[(size_t)n * 3 + 0] = p20 + bc0 * d1 + m10 * d2 + ba0 * d3;
  out_next[(size_t)n * 3 + 1] = p21 + bc1 * d1 + m11 * d2 + ba1 * d3;
  out_next[(size_t)n * 3 + 2] = p22 + bc2 * d1 + m12 * d2 + ba2 * d3;
}

#define NRES 256           // residues per kabsch block
#define NF (NRES * 45)     // floats per block slab (11520)
#define NF4 (NF / 4)       // float4s per block slab (2880)

__global__ __launch_bounds__(256) void rotamer_fused_kernel(
    const float* __restrict__ fixed, const float* __restrict__ mobile,
    const float* __restrict__ coords, const float* __restrict__ prev,
    const float* __restrict__ blen, const float* __restrict__ bang,
    const float* __restrict__ dihe, const float* __restrict__ degrees,
    float* __restrict__ out_aligned, float* __restrict__ out_next,
    f32x4* __restrict__ out_chi, int N, int KB, int total4) {
  int b = blockIdx.x;
  if (b < KB) {
    __shared__ __attribute__((aligned(16))) float lds[NF];
    int t = threadIdx.x;
    int n0 = b * NRES;
    if (n0 + NRES <= N) {
      // ---- cooperative aligned float4 load of the block's coords slab ----
      const f32x4* src = (const f32x4*)(coords + (size_t)n0 * 45);
      f32x4* ldsv = (f32x4*)lds;
#pragma unroll
      for (int i = 0; i < 12; ++i) {
        int idx = i * 256 + t;
        if (idx < NF4) ldsv[idx] = src[idx];
      }
      __syncthreads();
      // ---- per-thread: R, then transform own 45-float slice in place ----
      int n = n0 + t;
      float r00, r01, r02, r10, r11, r12, r20, r21, r22;
      float mc0, mc1, mc2, fc0, fc1, fc2;
      compute_R(fixed, mobile, n, r00, r01, r02, r10, r11, r12, r20, r21, r22,
                mc0, mc1, mc2, fc0, fc1, fc2);
      float* slice = lds + t * 45;
#pragma unroll
      for (int a = 0; a < 15; ++a) {
        float x = slice[a * 3 + 0] - mc0;
        float y = slice[a * 3 + 1] - mc1;
        float z = slice[a * 3 + 2] - mc2;
        slice[a * 3 + 0] = x * r00 + y * r10 + z * r20 + fc0;
        slice[a * 3 + 1] = x * r01 + y * r11 + z * r21 + fc1;
        slice[a * 3 + 2] = x * r02 + y * r12 + z * r22 + fc2;
      }
      nerf_next(prev, blen, bang, dihe, out_next, n);
      __syncthreads();
      // ---- cooperative aligned float4 nontemporal store ----
      f32x4* gout = (f32x4*)(out_aligned + (size_t)n0 * 45);
#pragma unroll
      for (int i = 0; i < 12; ++i) {
        int idx = i * 256 + t;
        if (idx < NF4) __builtin_nontemporal_store(ldsv[idx], &gout[idx]);
      }
    } else {
      // ---- partial last block: scalar fallback ----
      int n = n0 + t;
      if (n < N) {
        float r00, r01, r02, r10, r11, r12, r20, r21, r22;
        float mc0, mc1, mc2, fc0, fc1, fc2;
        compute_R(fixed, mobile, n, r00, r01, r02, r10, r11, r12, r20, r21,
                  r22, mc0, mc1, mc2, fc0, fc1, fc2);
        const float* cb = coords + (size_t)n * 45;
        float* ob = out_aligned + (size_t)n * 45;
#pragma unroll
        for (int a = 0; a < 15; ++a) {
          float x = cb[a * 3 + 0] - mc0;
          float y = cb[a * 3 + 1] - mc1;
          float z = cb[a * 3 + 2] - mc2;
          ob[a * 3 + 0] = x * r00 + y * r10 + z * r20 + fc0;
          ob[a * 3 + 1] = x * r01 + y * r11 + z * r21 + fc1;
          ob[a * 3 + 2] = x * r02 + y * r12 + z * r22 + fc2;
        }
        nerf_next(prev, blen, bang, dihe, out_next, n);
      }
    }
    return;
  }
  // ---- chi embedding: 1 thread = 1 aligned float4 of output ----
  int g = (b - KB) * 256 + threadIdx.x;
  if (g >= total4) return;
  unsigned ug = (unsigned)g;
  unsigned n = ug / 72u;
  unsigned rem = ug - n * 72u;
  unsigned k = rem / 18u;        // which angle
  unsigned q = rem - k * 18u;    // which float4 within the 72 bins
  float deg = degrees[n * 4u + k];
  float base = (float)(q * 20u) - 180.0f;
  f32x4 v;
#pragma unroll
  for (int j = 0; j < 4; ++j) {
    float center = base + 5.0f * (float)j;
    float tt = deg - center + 180.0f;   // in (-175, 540)
    tt = (tt < 0.0f) ? tt + 360.0f : tt;
    tt = (tt >= 360.0f) ? tt - 360.0f : tt;
    float dw = tt - 180.0f;
    v[j] = __expf(dw * dw * (-1.0f / 12.5f));
  }
  __builtin_nontemporal_store(v, &out_chi[g]);
}

extern "C" void kernel_launch(void* const* d_in, const int* in_sizes, int n_in,
                              void* d_out, int out_size, void* d_ws,
                              size_t ws_size, hipStream_t stream) {
  (void)n_in; (void)d_ws; (void)ws_size; (void)out_size;
  const float* fixed = (const float*)d_in[0];
  const float* mobile = (const float*)d_in[1];
  const float* coords = (const float*)d_in[2];
  const float* prev = (const float*)d_in[3];
  const float* blen = (const float*)d_in[4];
  const float* bang = (const float*)d_in[5];
  const float* dihe = (const float*)d_in[6];
  const float* degrees = (const float*)d_in[7];

  int N = in_sizes[0] / 9;
  float* out = (float*)d_out;
  float* out_aligned = out;                     // N*45
  float* out_next = out + (size_t)N * 45;       // N*3
  float* out_chi = out + (size_t)N * 48;        // N*288 (16B aligned)

  int KB = (N + NRES - 1) / NRES;               // kabsch blocks (first)
  int total4 = N * 72;
  int CB = (total4 + 255) / 256;                // chi blocks
  rotamer_fused_kernel<<<KB + CB, 256, 0, stream>>>(
      fixed, mobile, coords, prev, blen, bang, dihe, degrees,
      out_aligned, out_next, (f32x4*)out_chi, N, KB, total4);
}

// Round 7
// 110.452 us; speedup vs baseline: 2.5553x; 1.2312x over previous
//
#include <hip/hip_runtime.h>
#include <math.h>

// RotamerBuilder: fused single-dispatch kernel, INTERLEAVED block types.
//   Every 73rd block: Kabsch alignment + NeRF extension (1 thread/residue).
//   All other blocks: circular-RBF chi embedding (1 thread = 1 float4).
// Ratio 1563:112500 ~= 1:72, so each CU always co-hosts f64-VALU (kabsch)
// and store-stream (chi) work -> phases overlap instead of running serially
// (R4/R6 were ~kabsch 35us + chi 95us back-to-back).
//
// R5 lesson: NO nontemporal on non-16B-aligned streams (partial-line NT
// stores bypassed L2 merge: 784MB vs 541MB HBM writes). aligned-output uses
// plain scalar stores (L2 merges them); NT only on the aligned chi float4s.
// R6 lesson: no big static LDS in the fused kernel (it throttles chi blocks).
//
// Layout (out, float32, concatenated):
//   aligned     [N*45]  at offset 0
//   next_coords [N*3]   at offset N*45
//   chi_embed   [N*288] at offset N*48

typedef float f32x4 __attribute__((ext_vector_type(4)));

// Rank-2 closed-form Kabsch in f64 (no iterative Jacobi): null vector from
// best row-cross of C, one exact 2x2 Jacobi rotation on the deflated Gram.
__device__ __forceinline__ void kabsch_residue(
    const float* __restrict__ fixed, const float* __restrict__ mobile,
    const float* __restrict__ coords, const float* __restrict__ prev,
    const float* __restrict__ blen, const float* __restrict__ bang,
    const float* __restrict__ dihe,
    float* __restrict__ out_aligned, float* __restrict__ out_next, int n) {
  const float* fp = fixed + (size_t)n * 9;
  const float* mp = mobile + (size_t)n * 9;
  double f[3][3], m[3][3];
#pragma unroll
  for (int p = 0; p < 3; ++p)
#pragma unroll
    for (int i = 0; i < 3; ++i) {
      f[p][i] = (double)fp[p * 3 + i];
      m[p][i] = (double)mp[p * 3 + i];
    }
  double fc[3], mcm[3];
#pragma unroll
  for (int i = 0; i < 3; ++i) {
    fc[i] = (f[0][i] + f[1][i] + f[2][i]) * (1.0 / 3.0);
    mcm[i] = (m[0][i] + m[1][i] + m[2][i]) * (1.0 / 3.0);
  }
  double C[3][3];
#pragma unroll
  for (int i = 0; i < 3; ++i)
#pragma unroll
    for (int j = 0; j < 3; ++j) {
      double s = 0.0;
#pragma unroll
      for (int p = 0; p < 3; ++p) s += (m[p][i] - mcm[i]) * (f[p][j] - fc[j]);
      C[i][j] = s;
    }
  // null vector v3 = best row-cross of C (C has rank <= 2)
  double x01 = C[0][1]*C[1][2] - C[0][2]*C[1][1];
  double y01 = C[0][2]*C[1][0] - C[0][0]*C[1][2];
  double z01 = C[0][0]*C[1][1] - C[0][1]*C[1][0];
  double x02 = C[0][1]*C[2][2] - C[0][2]*C[2][1];
  double y02 = C[0][2]*C[2][0] - C[0][0]*C[2][2];
  double z02 = C[0][0]*C[2][1] - C[0][1]*C[2][0];
  double x12 = C[1][1]*C[2][2] - C[1][2]*C[2][1];
  double y12 = C[1][2]*C[2][0] - C[1][0]*C[2][2];
  double z12 = C[1][0]*C[2][1] - C[1][1]*C[2][0];
  double n01 = x01*x01 + y01*y01 + z01*z01;
  double n02 = x02*x02 + y02*y02 + z02*z02;
  double n12 = x12*x12 + y12*y12 + z12*z12;
  double vx = x01, vy = y01, vz = z01, nn = n01;
  if (n02 > nn) { vx = x02; vy = y02; vz = z02; nn = n02; }
  if (n12 > nn) { vx = x12; vy = y12; vz = z12; nn = n12; }
  double invn = 1.0 / sqrt(fmax(nn, 1e-300));
  vx *= invn; vy *= invn; vz *= invn;
  // orthonormal basis {w1,w2} perpendicular to v3
  double av0 = fabs(vx), av1 = fabs(vy), av2 = fabs(vz);
  double w10, w11, w12;
  if (av0 <= av1 && av0 <= av2) {
    w10 = 1.0 - vx*vx; w11 = -vx*vy; w12 = -vx*vz;
  } else if (av1 <= av2) {
    w10 = -vy*vx; w11 = 1.0 - vy*vy; w12 = -vy*vz;
  } else {
    w10 = -vz*vx; w11 = -vz*vy; w12 = 1.0 - vz*vz;
  }
  double iw = 1.0 / sqrt(fmax(w10*w10 + w11*w11 + w12*w12, 1e-300));
  w10 *= iw; w11 *= iw; w12 *= iw;
  double w20 = vy*w12 - vz*w11;
  double w21 = vz*w10 - vx*w12;
  double w22 = vx*w11 - vy*w10;
  // b_i = C w_i ; Gram 2x2 ; one exact Jacobi rotation
  double b10 = C[0][0]*w10 + C[0][1]*w11 + C[0][2]*w12;
  double b11 = C[1][0]*w10 + C[1][1]*w11 + C[1][2]*w12;
  double b12 = C[2][0]*w10 + C[2][1]*w11 + C[2][2]*w12;
  double b20 = C[0][0]*w20 + C[0][1]*w21 + C[0][2]*w22;
  double b21 = C[1][0]*w20 + C[1][1]*w21 + C[1][2]*w22;
  double b22 = C[2][0]*w20 + C[2][1]*w21 + C[2][2]*w22;
  double g00 = b10*b10 + b11*b11 + b12*b12;
  double g01 = b10*b20 + b11*b21 + b12*b22;
  double g11 = b20*b20 + b21*b21 + b22*b22;
  double c, s;
  if (fabs(g01) > 1e-300) {
    double tau = (g11 - g00) / (2.0 * g01);
    double tt = 1.0 / (fabs(tau) + sqrt(1.0 + tau * tau));
    if (tau < 0.0) tt = -tt;
    c = 1.0 / sqrt(1.0 + tt * tt);
    s = tt * c;
  } else {
    c = 1.0; s = 0.0;
  }
  double va0 = c*w10 - s*w20, va1 = c*w11 - s*w21, va2 = c*w12 - s*w22;
  double vb0 = s*w10 + c*w20, vb1 = s*w11 + c*w21, vb2 = s*w12 + c*w22;
  double Ca0 = c*b10 - s*b20, Ca1 = c*b11 - s*b21, Ca2 = c*b12 - s*b22;
  double Cb0 = s*b10 + c*b20, Cb1 = s*b11 + c*b21, Cb2 = s*b12 + c*b22;
  double ia = 1.0 / sqrt(fmax(Ca0*Ca0 + Ca1*Ca1 + Ca2*Ca2, 1e-300));
  double ua0 = Ca0 * ia, ua1 = Ca1 * ia, ua2 = Ca2 * ia;
  double pr = ua0*Cb0 + ua1*Cb1 + ua2*Cb2;
  double ub0 = Cb0 - pr*ua0, ub1 = Cb1 - pr*ua1, ub2 = Cb2 - pr*ua2;
  double ib = 1.0 / sqrt(fmax(ub0*ub0 + ub1*ub1 + ub2*ub2, 1e-300));
  ub0 *= ib; ub1 *= ib; ub2 *= ib;
  double uc0 = ua1*ub2 - ua2*ub1;
  double uc1 = ua2*ub0 - ua0*ub2;
  double uc2 = ua0*ub1 - ua1*ub0;
  double vc0 = va1*vb2 - va2*vb1;
  double vc1 = va2*vb0 - va0*vb2;
  double vc2 = va0*vb1 - va1*vb0;
  // R = ua va^T + ub vb^T + uc vc^T  (== Kabsch U diag(1,1,det) W^T)
  float r00 = (float)(ua0*va0 + ub0*vb0 + uc0*vc0);
  float r01 = (float)(ua0*va1 + ub0*vb1 + uc0*vc1);
  float r02 = (float)(ua0*va2 + ub0*vb2 + uc0*vc2);
  float r10 = (float)(ua1*va0 + ub1*vb0 + uc1*vc0);
  float r11 = (float)(ua1*va1 + ub1*vb1 + uc1*vc1);
  float r12 = (float)(ua1*va2 + ub1*vb2 + uc1*vc2);
  float r20 = (float)(ua2*va0 + ub2*vb0 + uc2*vc0);
  float r21 = (float)(ua2*va1 + ub2*vb1 + uc2*vc1);
  float r22 = (float)(ua2*va2 + ub2*vb2 + uc2*vc2);
  float mc0 = (float)mcm[0], mc1 = (float)mcm[1], mc2 = (float)mcm[2];
  float fc0 = (float)fc[0], fc1 = (float)fc[1], fc2 = (float)fc[2];

  // aligned = (coords - mob_com) @ R + fixed_com  (plain scalar I/O;
  // L2 merges the 180B-stride dwords — verified fast in R4)
  const float* cb = coords + (size_t)n * 45;
  float* ob = out_aligned + (size_t)n * 45;
#pragma unroll
  for (int a = 0; a < 15; ++a) {
    float x = cb[a * 3 + 0] - mc0;
    float y = cb[a * 3 + 1] - mc1;
    float z = cb[a * 3 + 2] - mc2;
    ob[a * 3 + 0] = x * r00 + y * r10 + z * r20 + fc0;
    ob[a * 3 + 1] = x * r01 + y * r11 + z * r21 + fc1;
    ob[a * 3 + 2] = x * r02 + y * r12 + z * r22 + fc2;
  }

  // next_coords (NeRF extension), f32
  const float* pp = prev + (size_t)n * 9;
  float p00 = pp[0], p01 = pp[1], p02 = pp[2];
  float p10 = pp[3], p11 = pp[4], p12 = pp[5];
  float p20 = pp[6], p21 = pp[7], p22 = pp[8];
  float bc0 = p10 - p20, bc1 = p11 - p21, bc2 = p12 - p22;
  float nb = sqrtf(bc0*bc0 + bc1*bc1 + bc2*bc2);
  float inb = 1.0f / (nb + 1e-6f);
  bc0 *= inb; bc1 *= inb; bc2 *= inb;
  float e0 = p10 - p00, e1 = p11 - p01, e2 = p12 - p02;
  float ba0 = e1 * bc2 - e2 * bc1;
  float ba1 = e2 * bc0 - e0 * bc2;
  float ba2 = e0 * bc1 - e1 * bc0;
  float nba = sqrtf(ba0*ba0 + ba1*ba1 + ba2*ba2);
  float inba = 1.0f / (nba + 1e-6f);
  ba0 *= inba; ba1 *= inba; ba2 *= inba;
  float m10 = ba1 * bc2 - ba2 * bc1;
  float m11 = ba2 * bc0 - ba0 * bc2;
  float m12 = ba0 * bc1 - ba1 * bc0;
  float L = blen[n], Aa = bang[n], D = dihe[n];
  float sA = sinf(Aa), cA = cosf(Aa), sD = sinf(D), cD = cosf(D);
  float d1 = L * cA;
  float d2 = L * sA * cD;
  float d3 = -L * sA * sD;
  out_next[(size_t)n * 3 + 0] = p20 + bc0 * d1 + m10 * d2 + ba0 * d3;
  out_next[(size_t)n * 3 + 1] = p21 + bc1 * d1 + m11 * d2 + ba1 * d3;
  out_next[(size_t)n * 3 + 2] = p22 + bc2 * d1 + m12 * d2 + ba2 * d3;
}

#define ILV 73   // 1 kabsch block per (ILV-1) chi blocks; KB*ILV >= KB+CB

__global__ __launch_bounds__(256) void rotamer_fused_kernel(
    const float* __restrict__ fixed, const float* __restrict__ mobile,
    const float* __restrict__ coords, const float* __restrict__ prev,
    const float* __restrict__ blen, const float* __restrict__ bang,
    const float* __restrict__ dihe, const float* __restrict__ degrees,
    float* __restrict__ out_aligned, float* __restrict__ out_next,
    f32x4* __restrict__ out_chi, int N, int KB, int total4) {
  int b = blockIdx.x;
  int kb = b / ILV;
  int rem = b - kb * ILV;
  if (rem == 0 && kb < KB) {
    // ---- kabsch block kb ----
    int n = kb * 256 + threadIdx.x;
    if (n < N)
      kabsch_residue(fixed, mobile, coords, prev, blen, bang, dihe,
                     out_aligned, out_next, n);
    return;
  }
  // ---- chi block: index = b minus the kabsch blocks dispatched before b ----
  int nkab = kb + 1;            // multiples of ILV in [0,b]
  if (nkab > KB) nkab = KB;
  int g = (b - nkab) * 256 + threadIdx.x;
  if (g >= total4) return;
  unsigned ug = (unsigned)g;
  unsigned n = ug / 72u;
  unsigned r2 = ug - n * 72u;
  unsigned k = r2 / 18u;         // which angle
  unsigned q = r2 - k * 18u;     // which float4 within the 72 bins
  float deg = degrees[n * 4u + k];
  float base = (float)(q * 20u) - 180.0f;
  f32x4 v;
#pragma unroll
  for (int j = 0; j < 4; ++j) {
    float center = base + 5.0f * (float)j;
    float t = deg - center + 180.0f;   // in (-175, 540)
    t = (t < 0.0f) ? t + 360.0f : t;
    t = (t >= 360.0f) ? t - 360.0f : t;
    float dw = t - 180.0f;
    v[j] = __expf(dw * dw * (-1.0f / 12.5f));
  }
  __builtin_nontemporal_store(v, &out_chi[g]);  // aligned full-line stream
}

extern "C" void kernel_launch(void* const* d_in, const int* in_sizes, int n_in,
                              void* d_out, int out_size, void* d_ws,
                              size_t ws_size, hipStream_t stream) {
  (void)n_in; (void)d_ws; (void)ws_size; (void)out_size;
  const float* fixed = (const float*)d_in[0];
  const float* mobile = (const float*)d_in[1];
  const float* coords = (const float*)d_in[2];
  const float* prev = (const float*)d_in[3];
  const float* blen = (const float*)d_in[4];
  const float* bang = (const float*)d_in[5];
  const float* dihe = (const float*)d_in[6];
  const float* degrees = (const float*)d_in[7];

  int N = in_sizes[0] / 9;
  float* out = (float*)d_out;
  float* out_aligned = out;                     // N*45
  float* out_next = out + (size_t)N * 45;       // N*3
  float* out_chi = out + (size_t)N * 48;        // N*288 (16B aligned)

  int KB = (N + 255) / 256;                     // kabsch blocks
  int total4 = N * 72;
  int CB = (total4 + 255) / 256;                // chi blocks
  // Interleave check: KB*ILV must cover KB+CB so every kabsch slot exists.
  // KB=1563, CB=112500 -> T=114063 <= 73*1563=114099. (static for this N)
  rotamer_fused_kernel<<<KB + CB, 256, 0, stream>>>(
      fixed, mobile, coords, prev, blen, bang, dihe, degrees,
      out_aligned, out_next, (f32x4*)out_chi, N, KB, total4);
}